// Round 2
// baseline (1558.994 us; speedup 1.0000x reference)
//
#include <hip/hip_runtime.h>

#define NN 2048
#define MM 2048
#define KC 8
#define DD 64
#define PN (NN + 4*KC + 32)
#define PM (MM + 4*KC + 32)
#define TOTROWS (2*(NN+MM))
#define CPAD (2*NN*MM + NN*NN + MM*MM + 6*(NN+MM) + 256)
#define PADV 3.0e38f
#define LN2F    0.6931471805599453f
#define INVLN2F 1.4426950408889634f
#define NSW 512               // sweep blocks: 4 waves/block, 4 rows/wave
#define RPW 4                 // rows per wave

// zr layout (ints): [8..15]=cnt_x, [16..23]=cnt_y, [24..31]=fill_x, [32..39]=fill_y
struct Params {
  const float* x; const float* centers; const float* ftarg;
  const float* y; const int* predy;
  float* out;
  int* zr;
  int* pred_x;
  int* cntx; int* cnty; int* off_x; int* off_y; int* pox; int* poy;
  int* bxy; int* byx; int* bxx; int* byy;    // per-cluster segment bases in Call
  int* tpre;                                 // 33-entry tile prefix table
  float* la; float* lb; int* valid; float* acc;
  float* part;                               // NSW per-block partials (no atomics)
  float* Xp; float* Yp; float* xn; float* yn;
  float* Fab; float* Faa; float* Gab; float* Gbb;   // ping-pong 2*PN / 2*PM
  int4* meta;   // per-row {coff, hoff, rs, bitcast(hb2)}
  float* fin;   // per-row final scale (0 if invalid)
  int* dsti;    // per-row destination index in padded potential array
  int* bsync;   // [0]=gen, [64..64+NSW-1]=per-block arrival flags (monotone)
  float* Call;
};

__device__ __forceinline__ float wredmax(float v){
  #pragma unroll
  for(int m=32;m>=1;m>>=1) v = fmaxf(v, __shfl_xor(v,m,64));
  return v;
}
__device__ __forceinline__ float wredsum(float v){
  #pragma unroll
  for(int m=32;m>=1;m>>=1) v += __shfl_xor(v,m,64);
  return v;
}

// ---- manual grid barrier (graph-capture-safe; monotone targets, no resets) ----
// release: __threadfence() lowers to agent-scope wb (writes visible via L3);
// acquire: __threadfence() after observing gen invalidates L1/L2 so plain
// potential loads next iteration see remote writes. Standard flag/gen scheme.
__device__ __forceinline__ void gbar(int* bsync, int target){
  __syncthreads();
  __threadfence();
  if(threadIdx.x==0)
    __hip_atomic_store(&bsync[64+blockIdx.x], target, __ATOMIC_RELAXED, __HIP_MEMORY_SCOPE_AGENT);
  if(blockIdx.x==0){
    for(int i=threadIdx.x; i<NSW; i+=256)
      while(__hip_atomic_load(&bsync[64+i], __ATOMIC_RELAXED, __HIP_MEMORY_SCOPE_AGENT) < target)
        __builtin_amdgcn_s_sleep(1);
    __syncthreads();
    if(threadIdx.x==0)
      __hip_atomic_store(&bsync[0], target, __ATOMIC_RELAXED, __HIP_MEMORY_SCOPE_AGENT);
  }
  if(threadIdx.x==0)
    while(__hip_atomic_load(&bsync[0], __ATOMIC_RELAXED, __HIP_MEMORY_SCOPE_AGENT) < target)
      __builtin_amdgcn_s_sleep(1);
  __syncthreads();
  __threadfence();
}

// ---------------- k_pred: zero potentials/sync + kmeans predict + LDS-hist counts ----------------
__global__ void __launch_bounds__(256) k_pred(Params p){
  __shared__ int hx[KC], hy[KC];
  const int tid = threadIdx.x;
  const int gtid = blockIdx.x*blockDim.x + tid;
  const int nth  = gridDim.x*blockDim.x;

  if(tid<KC){ hx[tid]=0; hy[tid]=0; }
  __syncthreads();

  for(int i=gtid;i<2*PN;i+=nth){ p.Fab[i]=0.f; p.Faa[i]=0.f; }
  for(int j=gtid;j<2*PM;j+=nth){ p.Gab[j]=0.f; p.Gbb[j]=0.f; }
  for(int i=gtid;i<64+NSW;i+=nth) p.bsync[i]=0;

  for(int i=gtid;i<NN;i+=nth){
    const float4* xi = (const float4*)(p.x + i*DD);
    float best = 3.4e38f; int bk = 0;
    for(int k=0;k<KC;k++){
      const float4* ck = (const float4*)(p.centers + k*DD);
      float s = 0.f;
      #pragma unroll
      for(int q=0;q<DD/4;q++){ float4 a=xi[q], b=ck[q];
        float dx=a.x-b.x, dy=a.y-b.y, dz=a.z-b.z, dw=a.w-b.w;
        s += dx*dx+dy*dy+dz*dz+dw*dw; }
      if(s < best){ best = s; bk = k; }
    }
    p.pred_x[i] = bk;
    atomicAdd(&hx[bk], 1);
  }
  for(int j=gtid;j<MM;j+=nth) atomicAdd(&hy[p.predy[j]], 1);
  __syncthreads();
  if(tid<KC   && hx[tid])    atomicAdd(&p.zr[8+tid], hx[tid]);
  if(tid>=KC && tid<2*KC && hy[tid-KC]) atomicAdd(&p.zr[16+tid-KC], hy[tid-KC]);
}

// ---------------- k_pack: redundant serial phase + block-reserved pack + row meta ----------------
__global__ void __launch_bounds__(256) k_pack(Params p){
  __shared__ int scx[KC], scy[KC];
  __shared__ int sox[KC+1], soy[KC+1], spx[KC], spy[KC];
  __shared__ int sbxy[KC], sbyx[KC], sbxx[KC], sbyy[KC], sval[KC];
  __shared__ float sla[KC], slb[KC];
  __shared__ int hbx[KC], hby[KC], basex[KC], basey[KC], curx[KC], cury[KC];
  const int tid = threadIdx.x;
  const int gtid = blockIdx.x*blockDim.x + tid;
  const int nth  = gridDim.x*blockDim.x;

  if(tid==0){
    int ox=0, oy=0, px=0, py=0; float lf=0.f;
    for(int k=0;k<KC;k++){
      int nk=p.zr[8+k], mk=p.zr[16+k];
      scx[k]=nk; scy[k]=mk;
      sox[k]=ox; soy[k]=oy; spx[k]=px; spy[k]=py;
      ox+=nk; oy+=mk; px=(px+nk+3)&~3; py=(py+mk+3)&~3;
      sla[k] = -logf(fmaxf((float)nk,1.f));
      slb[k] = -logf(fmaxf((float)mk,1.f));
      sval[k] = (nk>0 && mk>0)?1:0;
      float df = (float)nk/(float)NN - p.ftarg[k];
      lf += df*df;
    }
    sox[KC]=ox; soy[KC]=oy;
    int run=0;
    for(int k=0;k<KC;k++){ int nk=scx[k], mk=scy[k]; sbxy[k]=run; run+=nk*((mk+3)&~3); }
    for(int k=0;k<KC;k++){ int nk=scx[k], mk=scy[k]; sbyx[k]=run; run+=mk*((nk+3)&~3); }
    for(int k=0;k<KC;k++){ int nk=scx[k];            sbxx[k]=run; run+=nk*((nk+3)&~3); }
    for(int k=0;k<KC;k++){ int mk=scy[k];            sbyy[k]=run; run+=mk*((mk+3)&~3); }
    if(blockIdx.x==0){
      for(int k=0;k<KC;k++){
        p.cntx[k]=scx[k]; p.cnty[k]=scy[k];
        p.off_x[k]=sox[k]; p.off_y[k]=soy[k];
        p.pox[k]=spx[k]; p.poy[k]=spy[k];
        p.bxy[k]=sbxy[k]; p.byx[k]=sbyx[k]; p.bxx[k]=sbxx[k]; p.byy[k]=sbyy[k];
        p.la[k]=sla[k]; p.lb[k]=slb[k]; p.valid[k]=sval[k];
      }
      int trun=0;
      for(int e=0;e<32;e++){
        int seg=e>>3, k=e&7;
        int nk=scx[k], mk=scy[k];
        int nrows = (seg==0)?nk:(seg==1)?mk:(seg==2)?nk:mk;
        int rs    = (seg==0)?((mk+3)&~3):(seg==1)?((nk+3)&~3):(seg==2)?((nk+3)&~3):((mk+3)&~3);
        p.tpre[e]=trun;
        trun += ((nrows+63)>>6) * ((rs+63)>>6);
      }
      p.tpre[32]=trun;
      *p.acc = lf/(float)KC;
    }
  }
  if(tid<KC){ hbx[tid]=0; hby[tid]=0; curx[tid]=0; cury[tid]=0; }
  __syncthreads();

  // pass 1: this block's per-cluster counts (LDS atomics only)
  for(int i=gtid;i<NN;i+=nth) atomicAdd(&hbx[p.pred_x[i]],1);
  for(int j=gtid;j<MM;j+=nth) atomicAdd(&hby[p.predy[j]],1);
  __syncthreads();
  // reserve global ranges: ONE device atomic per (block,cluster)
  if(tid<KC){
    basex[tid] = sox[tid] + (hbx[tid] ? atomicAdd(&p.zr[24+tid], hbx[tid]) : 0);
    basey[tid] = soy[tid] + (hby[tid] ? atomicAdd(&p.zr[32+tid], hby[tid]) : 0);
  }
  __syncthreads();

  // pass 2: place points (LDS cursors; pack order within cluster is irrelevant)
  for(int i=gtid;i<NN;i+=nth){
    int k=p.pred_x[i];
    int pos = basex[k] + atomicAdd(&curx[k],1);
    const float4* xi=(const float4*)(p.x+i*DD);
    float4* dst=(float4*)(p.Xp+(size_t)pos*DD);
    float s=0.f;
    #pragma unroll
    for(int q=0;q<DD/4;q++){ float4 v=xi[q]; dst[q]=v;
      s += v.x*v.x+v.y*v.y+v.z*v.z+v.w*v.w; }
    p.xn[pos]=s;
  }
  for(int j=gtid;j<MM;j+=nth){
    int k=p.predy[j];
    int pos = basey[k] + atomicAdd(&cury[k],1);
    const float4* yj=(const float4*)(p.y+j*DD);
    float4* dst=(float4*)(p.Yp+(size_t)pos*DD);
    float s=0.f;
    #pragma unroll
    for(int q=0;q<DD/4;q++){ float4 v=yj[q]; dst[q]=v;
      s += v.x*v.x+v.y*v.y+v.z*v.z+v.w*v.w; }
    p.yn[pos]=s;
  }

  // per-row metadata
  for(int row=gtid; row<TOTROWS; row+=nth){
    int grp = (row>=NN) + (row>=NN+MM) + (row>=2*NN+MM);
    int pidx = row - ((grp==0)?0:(grp==1)?NN:(grp==2)?(NN+MM):(2*NN+MM));
    const int* offs = (grp==0||grp==2)? sox : soy;
    int k=0;
    #pragma unroll
    for(int q=1;q<KC;q++) if(pidx>=offs[q]) k=q;
    int r = pidx - offs[k];
    int nk=scx[k], mk=scy[k];
    int rsx=(nk+3)&~3, rsy=(mk+3)&~3;
    int coff, rs, di; float hc, fv; int hoff;
    if(grp==0){ rs=rsy; coff=sbxy[k]+r*rs; hoff=spy[k]; hc=slb[k]; di=spx[k]+r;
      fv = sval[k] ?  1.f/(float)nk : 0.f; }
    else if(grp==1){ rs=rsx; coff=sbyx[k]+r*rs; hoff=spx[k]; hc=sla[k]; di=spy[k]+r;
      fv = sval[k] ?  1.f/(float)mk : 0.f; }
    else if(grp==2){ rs=rsx; coff=sbxx[k]+r*rs; hoff=spx[k]; hc=sla[k]; di=spx[k]+r;
      fv = sval[k] ? -1.f/(float)nk : 0.f; }
    else { rs=rsy; coff=sbyy[k]+r*rs; hoff=spy[k]; hc=slb[k]; di=spy[k]+r;
      fv = sval[k] ? -1.f/(float)mk : 0.f; }
    p.meta[row] = make_int4(coff, hoff, rs, __float_as_int(hc*INVLN2F));
    p.fin[row]  = fv;
    p.dsti[row] = di;
  }
}

// ---------------- k4: LDS-tiled cost build (64x64 tiles, B transposed) ----------------
__global__ void __launch_bounds__(256) k4_cost(Params p){
  __shared__ float As[64*68];
  __shared__ float Bt[64*68];
  const int tid = threadIdx.x;
  const int T = p.tpre[32];

  for(int tile=blockIdx.x; tile<T; tile+=gridDim.x){
    int e=0;
    for(int q=1;q<32;q++) if(tile>=p.tpre[q]) e=q;
    int seg=e>>3, k=e&7;
    int nk=p.cntx[k], mk=p.cnty[k];
    int rsx=(nk+3)&~3, rsy=(mk+3)&~3;
    const float *Apts, *Bpts, *nA, *nB; int nrows, ncol, rs, base;
    if(seg==0){ Apts=p.Xp+(size_t)p.off_x[k]*DD; Bpts=p.Yp+(size_t)p.off_y[k]*DD;
      nA=p.xn+p.off_x[k]; nB=p.yn+p.off_y[k]; nrows=nk; ncol=mk; rs=rsy; base=p.bxy[k]; }
    else if(seg==1){ Apts=p.Yp+(size_t)p.off_y[k]*DD; Bpts=p.Xp+(size_t)p.off_x[k]*DD;
      nA=p.yn+p.off_y[k]; nB=p.xn+p.off_x[k]; nrows=mk; ncol=nk; rs=rsx; base=p.byx[k]; }
    else if(seg==2){ Apts=p.Xp+(size_t)p.off_x[k]*DD; Bpts=Apts;
      nA=p.xn+p.off_x[k]; nB=nA; nrows=nk; ncol=nk; rs=rsx; base=p.bxx[k]; }
    else { Apts=p.Yp+(size_t)p.off_y[k]*DD; Bpts=Apts;
      nA=p.yn+p.off_y[k]; nB=nA; nrows=mk; ncol=mk; rs=rsy; base=p.byy[k]; }
    int ntc=(rs+63)>>6;
    int lt = tile - p.tpre[e];
    int tr = lt/ntc, tc = lt - tr*ntc;

    __syncthreads();
    for(int l=tid;l<1024;l+=256){
      int row=l>>4, c4=l&15;
      int gA=tr*64+row;
      float4 va = (gA<nrows)? ((const float4*)Apts)[gA*16+c4] : make_float4(0.f,0.f,0.f,0.f);
      *(float4*)&As[row*68 + c4*4] = va;
      int gB=tc*64+row;
      float4 vb = (gB<ncol)? ((const float4*)Bpts)[gB*16+c4] : make_float4(0.f,0.f,0.f,0.f);
      Bt[(c4*4+0)*68+row]=vb.x; Bt[(c4*4+1)*68+row]=vb.y;
      Bt[(c4*4+2)*68+row]=vb.z; Bt[(c4*4+3)*68+row]=vb.w;
    }
    __syncthreads();

    int tx=tid&15, ty=tid>>4;
    float4 acc[4] = {make_float4(0,0,0,0),make_float4(0,0,0,0),
                     make_float4(0,0,0,0),make_float4(0,0,0,0)};
    for(int kk=0;kk<64;kk+=4){
      float4 a0=*(float4*)&As[(ty*4+0)*68+kk];
      float4 a1=*(float4*)&As[(ty*4+1)*68+kk];
      float4 a2=*(float4*)&As[(ty*4+2)*68+kk];
      float4 a3=*(float4*)&As[(ty*4+3)*68+kk];
      float4 b0=*(float4*)&Bt[(kk+0)*68+tx*4];
      float4 b1=*(float4*)&Bt[(kk+1)*68+tx*4];
      float4 b2=*(float4*)&Bt[(kk+2)*68+tx*4];
      float4 b3=*(float4*)&Bt[(kk+3)*68+tx*4];
      #define ACCROW(i,AI) \
        acc[i].x = fmaf(AI.x,b0.x, fmaf(AI.y,b1.x, fmaf(AI.z,b2.x, fmaf(AI.w,b3.x, acc[i].x)))); \
        acc[i].y = fmaf(AI.x,b0.y, fmaf(AI.y,b1.y, fmaf(AI.z,b2.y, fmaf(AI.w,b3.y, acc[i].y)))); \
        acc[i].z = fmaf(AI.x,b0.z, fmaf(AI.y,b1.z, fmaf(AI.z,b2.z, fmaf(AI.w,b3.z, acc[i].z)))); \
        acc[i].w = fmaf(AI.x,b0.w, fmaf(AI.y,b1.w, fmaf(AI.z,b2.w, fmaf(AI.w,b3.w, acc[i].w))));
      ACCROW(0,a0) ACCROW(1,a1) ACCROW(2,a2) ACCROW(3,a3)
      #undef ACCROW
    }

    int gc0 = tc*64 + tx*4;
    #pragma unroll
    for(int i=0;i<4;i++){
      int gr = tr*64 + ty*4 + i;
      if(gr >= nrows) continue;
      float xr = nA[gr];
      float v[4]; float d[4]={acc[i].x,acc[i].y,acc[i].z,acc[i].w};
      #pragma unroll
      for(int j=0;j<4;j++){
        int gc = gc0+j;
        v[j] = PADV;
        if(gc < ncol) v[j] = 0.5f*fmaxf(xr + nB[gc] - 2.f*d[j], 0.f);
      }
      if(gc0+3 < rs){
        *(float4*)&p.Call[(size_t)base + (size_t)gr*rs + gc0] = make_float4(v[0],v[1],v[2],v[3]);
      } else {
        for(int j=0;j<4;j++) if(gc0+j < rs) p.Call[(size_t)base + (size_t)gr*rs + gc0+j] = v[j];
      }
    }
  }
}

// value-form online-LSE step: C chunk held in registers across iterations
#define LSE_CORE(cv,pv,hi,mi,si) { \
  float w0=fmaf((pv).x-(cv).x,s1,hi), w1=fmaf((pv).y-(cv).y,s1,hi); \
  float w2=fmaf((pv).z-(cv).z,s1,hi), w3=fmaf((pv).w-(cv).w,s1,hi); \
  float lm=fmaxf(fmaxf(w0,w1),fmaxf(w2,w3)); \
  float mn=fmaxf(mi,lm); \
  si = si*exp2f(mi-mn) + (exp2f(w0-mn)+exp2f(w1-mn)) + (exp2f(w2-mn)+exp2f(w3-mn)); \
  mi = mn; }

// ---------------- k_sweep: ALL eps steps + final extrapolation + output, ONE plain kernel ----------------
// 512 blocks (co-residency needs only ~171 CUs at 3 blocks/CU), manual flag/gen
// barrier between Jacobi steps. Each wave owns 4 rows; C rows staged ONCE in
// registers (<=512 cols fast path), own-potential carried in registers, so
// per-iteration global traffic is only the ~34KB of opposite-side potentials.
__global__ void __launch_bounds__(256, 3) k_sweep(Params p){
  __shared__ float sp[4];
  const int tid  = threadIdx.x;
  const int lane = tid & 63;
  const int wv   = tid >> 6;
  const int w    = blockIdx.x*4 + wv;        // wave id 0..2047
  const int rbase = w*RPW;
  const int grp = (rbase>=NN) + (rbase>=NN+MM) + (rbase>=2*NN+MM);  // groups aligned to 4

  const float* poBase; int poN; float* fam; int famN;
  if(grp==0){ poBase=p.Gab; poN=PM; fam=p.Fab; famN=PN; }
  else if(grp==1){ poBase=p.Fab; poN=PN; fam=p.Gab; famN=PM; }
  else if(grp==2){ poBase=p.Faa; poN=PN; fam=p.Faa; famN=PN; }
  else          { poBase=p.Gbb; poN=PM; fam=p.Gbb; famN=PM; }

  int coff[RPW], hof[RPW], rs[RPW], dst[RPW];
  float h[RPW], fv[RPW];
  int rsm = 0;
  #pragma unroll
  for(int j=0;j<RPW;j++){
    int4 mt = p.meta[rbase+j];
    coff[j]=mt.x; hof[j]=mt.y; rs[j]=mt.z; h[j]=__int_as_float(mt.w);
    dst[j]=p.dsti[rbase+j]; fv[j]=p.fin[rbase+j];
    rsm = rs[j]>rsm ? rs[j] : rsm;
  }

  // ---- stage C rows in registers (fast path: rsm <= 512 -> 2 chunks/lane/row) ----
  const int c0a = lane*4, c0b = lane*4 + 256;
  const bool staged = (rsm <= 512);   // wave-uniform
  const bool two    = (rsm > 256);    // wave-uniform
  const float4 PAD4 = make_float4(PADV,PADV,PADV,PADV);
  float4 cva[RPW], cvb[RPW];
  #pragma unroll
  for(int j=0;j<RPW;j++){ cva[j]=PAD4; cvb[j]=PAD4; }
  if(staged){
    #pragma unroll
    for(int j=0;j<RPW;j++){
      if(c0a<rs[j]) cva[j] = *(const float4*)(p.Call+coff[j]+c0a);
      if(two && c0b<rs[j]) cvb[j] = *(const float4*)(p.Call+coff[j]+c0b);
    }
  }
  // Padded lanes (cv=PADV, pv=0): w is hugely negative/-inf; their si terms are
  // annihilated by exp2f(m-M) in the cross-lane rescale -> exact match with the
  // guarded stream loop.

  const double EMIND = 0.05*0.05, S2D = 0.8*0.8;
  float f[RPW];
  #pragma unroll
  for(int j=0;j<RPW;j++) f[j]=0.f;

  double e = 16.0; int it = 0;
  for(;;){
    const bool last = !(e > EMIND);
    const float eps = last ? (float)EMIND : (float)e;
    const float s1 = (1.0f/eps)*INVLN2F;
    const int cur = it & 1;
    const float* po = poBase + cur*poN;

    float m[RPW], s[RPW];
    #pragma unroll
    for(int j=0;j<RPW;j++){ m[j]=-3.4e38f; s[j]=0.f; }
    if(staged){
      #pragma unroll
      for(int j=0;j<RPW;j++){
        float4 pv = (c0a<rs[j])? *(const float4*)(po+hof[j]+c0a) : make_float4(0.f,0.f,0.f,0.f);
        LSE_CORE(cva[j], pv, h[j], m[j], s[j])
      }
      if(two){
        #pragma unroll
        for(int j=0;j<RPW;j++){
          float4 pv = (c0b<rs[j])? *(const float4*)(po+hof[j]+c0b) : make_float4(0.f,0.f,0.f,0.f);
          LSE_CORE(cvb[j], pv, h[j], m[j], s[j])
        }
      }
    } else {
      for(int c0=lane*4; c0<rsm; c0+=256){
        #pragma unroll
        for(int j=0;j<RPW;j++){
          if(c0<rs[j]){
            float4 cv=*(const float4*)(p.Call+coff[j]+c0);
            float4 pv=*(const float4*)(po+hof[j]+c0);
            LSE_CORE(cv, pv, h[j], m[j], s[j])
          }
        }
      }
    }
    #pragma unroll
    for(int j=0;j<RPW;j++){
      float M=wredmax(m[j]);
      float S=wredsum(s[j]*exp2f(m[j]-M));
      f[j] = 0.5f*(f[j] + (-eps*LN2F*(M + log2f(S))));
    }
    if(lane==0){
      float* fn = fam + (1-cur)*famN;
      #pragma unroll
      for(int j=0;j<RPW;j++) fn[dst[j]] = f[j];
    }
    ++it;
    gbar(p.bsync, it);
    if(last) break;
    e *= S2D;
  }

  // ---- final extrapolation at eps_min (cur = ne&1 = it&1), per-block partial ----
  {
    const float eps = (float)EMIND;
    const float s1 = (1.0f/eps)*INVLN2F;
    const int cur = it & 1;
    const float* po = poBase + cur*poN;

    float m[RPW], s[RPW];
    #pragma unroll
    for(int j=0;j<RPW;j++){ m[j]=-3.4e38f; s[j]=0.f; }
    if(staged){
      #pragma unroll
      for(int j=0;j<RPW;j++){
        float4 pv = (c0a<rs[j])? *(const float4*)(po+hof[j]+c0a) : make_float4(0.f,0.f,0.f,0.f);
        LSE_CORE(cva[j], pv, h[j], m[j], s[j])
      }
      if(two){
        #pragma unroll
        for(int j=0;j<RPW;j++){
          float4 pv = (c0b<rs[j])? *(const float4*)(po+hof[j]+c0b) : make_float4(0.f,0.f,0.f,0.f);
          LSE_CORE(cvb[j], pv, h[j], m[j], s[j])
        }
      }
    } else {
      for(int c0=lane*4; c0<rsm; c0+=256){
        #pragma unroll
        for(int j=0;j<RPW;j++){
          if(c0<rs[j]){
            float4 cv=*(const float4*)(p.Call+coff[j]+c0);
            float4 pv=*(const float4*)(po+hof[j]+c0);
            LSE_CORE(cv, pv, h[j], m[j], s[j])
          }
        }
      }
    }
    float pr = 0.f;
    #pragma unroll
    for(int j=0;j<RPW;j++){
      float M=wredmax(m[j]);
      float S=wredsum(s[j]*exp2f(m[j]-M));
      if(fv[j]!=0.f) pr += fv[j]*(-eps*LN2F*(M + log2f(S)));
    }
    if(lane==0) sp[wv] = pr;
    __syncthreads();
    if(tid==0)
      p.part[blockIdx.x] = sp[0]+sp[1]+sp[2]+sp[3];
  }
  gbar(p.bsync, it+1);

  // ---- output: block 0 sums partials + filling loss ----
  if(blockIdx.x==0){
    float s=0.f;
    for(int i=tid;i<NSW;i+=256) s += p.part[i];
    s = wredsum(s);
    if((tid&63)==0) sp[tid>>6]=s;
    __syncthreads();
    if(tid==0)
      p.out[0] = sp[0]+sp[1]+sp[2]+sp[3] + *p.acc;
  }
}

extern "C" void kernel_launch(void* const* d_in, const int* in_sizes, int n_in,
                              void* d_out, int out_size, void* d_ws, size_t ws_size,
                              hipStream_t stream)
{
  Params p;
  p.x       = (const float*)d_in[0];
  p.centers = (const float*)d_in[1];
  p.ftarg   = (const float*)d_in[2];
  p.y       = (const float*)d_in[3];
  p.predy   = (const int*)d_in[4];
  p.out     = (float*)d_out;

  char* w = (char*)d_ws; size_t o = 0;
  auto A = [&](size_t bytes)->char*{ char* r = w + o; o = (o + bytes + 255) & ~(size_t)255; return r; };
  p.zr   =(int*)A(64*4);
  p.pred_x=(int*)A(NN*4);
  p.cntx =(int*)A(KC*4); p.cnty=(int*)A(KC*4);
  p.off_x=(int*)A(KC*4); p.off_y=(int*)A(KC*4);
  p.pox  =(int*)A(KC*4); p.poy =(int*)A(KC*4);
  p.bxy  =(int*)A(KC*4); p.byx =(int*)A(KC*4);
  p.bxx  =(int*)A(KC*4); p.byy =(int*)A(KC*4);
  p.tpre =(int*)A(33*4);
  p.la=(float*)A(KC*4); p.lb=(float*)A(KC*4); p.valid=(int*)A(KC*4);
  p.acc=(float*)A(4);
  p.part=(float*)A(NSW*4);
  p.Xp=(float*)A((size_t)NN*DD*4); p.Yp=(float*)A((size_t)MM*DD*4);
  p.xn=(float*)A(NN*4); p.yn=(float*)A(MM*4);
  p.Fab=(float*)A((size_t)2*PN*4); p.Faa=(float*)A((size_t)2*PN*4);
  p.Gab=(float*)A((size_t)2*PM*4); p.Gbb=(float*)A((size_t)2*PM*4);
  p.meta=(int4*)A((size_t)TOTROWS*16);
  p.fin =(float*)A((size_t)TOTROWS*4);
  p.dsti=(int*)A((size_t)TOTROWS*4);
  p.bsync=(int*)A((64+NSW)*4);
  p.Call=(float*)A((size_t)CPAD*4);

  hipMemsetAsync(p.zr, 0, 64*4, stream);
  hipLaunchKernelGGL(k_pred,  dim3(16),  dim3(256), 0, stream, p);
  hipLaunchKernelGGL(k_pack,  dim3(32),  dim3(256), 0, stream, p);
  hipLaunchKernelGGL(k4_cost, dim3(512), dim3(256), 0, stream, p);
  hipLaunchKernelGGL(k_sweep, dim3(NSW), dim3(256), 0, stream, p);
}

// Round 3
// 324.891 us; speedup vs baseline: 4.7985x; 4.7985x over previous
//
#include <hip/hip_runtime.h>

#define NN 2048
#define MM 2048
#define KC 8
#define DD 64
#define PN (NN + 4*KC + 32)
#define PM (MM + 4*KC + 32)
#define TOTROWS (2*(NN+MM))
#define CPAD (2*NN*MM + NN*NN + MM*MM + 6*(NN+MM) + 256)
#define PADV 3.0e38f
#define LN2F    0.6931471805599453f
#define INVLN2F 1.4426950408889634f
#define NSW 512               // sweep blocks: 4 waves/block, 4 rows/wave
#define RPW 4                 // rows per wave

// zr layout (ints): [8..15]=cnt_x, [16..23]=cnt_y, [24..31]=fill_x, [32..39]=fill_y
struct Params {
  const float* x; const float* centers; const float* ftarg;
  const float* y; const int* predy;
  float* out;
  int* zr;
  int* pred_x;
  int* cntx; int* cnty; int* off_x; int* off_y; int* pox; int* poy;
  int* bxy; int* byx; int* bxx; int* byy;    // per-cluster segment bases in Call
  int* tpre;                                 // 33-entry tile prefix table
  float* la; float* lb; int* valid; float* acc;
  float* part;                               // NSW per-block partials (no atomics)
  float* Xp; float* Yp; float* xn; float* yn;
  float* Fab; float* Faa; float* Gab; float* Gbb;   // ping-pong 2*PN / 2*PM
  int4* meta;   // per-row {coff, hoff, rs, bitcast(hb2)}
  float* fin;   // per-row final scale (0 if invalid)
  int* dsti;    // per-row destination index in padded potential array
  int* bsync;   // [0]=gen, [64..64+NSW-1]=per-block arrival flags (monotone)
  float* Call;
};

__device__ __forceinline__ float wredmax(float v){
  #pragma unroll
  for(int m=32;m>=1;m>>=1) v = fmaxf(v, __shfl_xor(v,m,64));
  return v;
}
__device__ __forceinline__ float wredsum(float v){
  #pragma unroll
  for(int m=32;m>=1;m>>=1) v += __shfl_xor(v,m,64);
  return v;
}

// coherent (LLC-resident, L1/L2-bypassing) scalar ops. All cross-block
// communication uses these -> NO cache fences needed anywhere.
__device__ __forceinline__ void st_coh(float* a, float v){
  __hip_atomic_store(a, v, __ATOMIC_RELAXED, __HIP_MEMORY_SCOPE_AGENT);
}
__device__ __forceinline__ float ld_coh(const float* a){
  return __hip_atomic_load(a, __ATOMIC_RELAXED, __HIP_MEMORY_SCOPE_AGENT);
}
__device__ __forceinline__ float4 ld_coh4(const float* a){
  float4 r;
  r.x = ld_coh(a+0); r.y = ld_coh(a+1); r.z = ld_coh(a+2); r.w = ld_coh(a+3);
  return r;
}

// ---- fence-free grid barrier (graph-capture-safe; monotone targets) ----
// __syncthreads() drains each wave's vmcnt (so this block's sc0sc1 data
// stores are at the LLC) before thread 0 publishes the arrival flag. Both
// flags and data bypass L1/L2, so flag observation => data visibility.
__device__ __forceinline__ void gbar(int* bsync, int target){
  __syncthreads();
  if(threadIdx.x==0)
    __hip_atomic_store(&bsync[64+blockIdx.x], target, __ATOMIC_RELAXED, __HIP_MEMORY_SCOPE_AGENT);
  if(blockIdx.x==0){
    for(int i=threadIdx.x; i<NSW; i+=256)
      while(__hip_atomic_load(&bsync[64+i], __ATOMIC_RELAXED, __HIP_MEMORY_SCOPE_AGENT) < target)
        __builtin_amdgcn_s_sleep(1);
    __syncthreads();
    if(threadIdx.x==0)
      __hip_atomic_store(&bsync[0], target, __ATOMIC_RELAXED, __HIP_MEMORY_SCOPE_AGENT);
  } else if(threadIdx.x==0){
    while(__hip_atomic_load(&bsync[0], __ATOMIC_RELAXED, __HIP_MEMORY_SCOPE_AGENT) < target)
      __builtin_amdgcn_s_sleep(1);
  }
  __syncthreads();
}

// ---------------- k_pred: zero potentials/sync + kmeans predict + LDS-hist counts ----------------
__global__ void __launch_bounds__(256) k_pred(Params p){
  __shared__ int hx[KC], hy[KC];
  const int tid = threadIdx.x;
  const int gtid = blockIdx.x*blockDim.x + tid;
  const int nth  = gridDim.x*blockDim.x;

  if(tid<KC){ hx[tid]=0; hy[tid]=0; }
  __syncthreads();

  for(int i=gtid;i<2*PN;i+=nth){ p.Fab[i]=0.f; p.Faa[i]=0.f; }
  for(int j=gtid;j<2*PM;j+=nth){ p.Gab[j]=0.f; p.Gbb[j]=0.f; }
  for(int i=gtid;i<64+NSW;i+=nth) p.bsync[i]=0;

  for(int i=gtid;i<NN;i+=nth){
    const float4* xi = (const float4*)(p.x + i*DD);
    float best = 3.4e38f; int bk = 0;
    for(int k=0;k<KC;k++){
      const float4* ck = (const float4*)(p.centers + k*DD);
      float s = 0.f;
      #pragma unroll
      for(int q=0;q<DD/4;q++){ float4 a=xi[q], b=ck[q];
        float dx=a.x-b.x, dy=a.y-b.y, dz=a.z-b.z, dw=a.w-b.w;
        s += dx*dx+dy*dy+dz*dz+dw*dw; }
      if(s < best){ best = s; bk = k; }
    }
    p.pred_x[i] = bk;
    atomicAdd(&hx[bk], 1);
  }
  for(int j=gtid;j<MM;j+=nth) atomicAdd(&hy[p.predy[j]], 1);
  __syncthreads();
  if(tid<KC   && hx[tid])    atomicAdd(&p.zr[8+tid], hx[tid]);
  if(tid>=KC && tid<2*KC && hy[tid-KC]) atomicAdd(&p.zr[16+tid-KC], hy[tid-KC]);
}

// ---------------- k_pack: redundant serial phase + block-reserved pack + row meta ----------------
__global__ void __launch_bounds__(256) k_pack(Params p){
  __shared__ int scx[KC], scy[KC];
  __shared__ int sox[KC+1], soy[KC+1], spx[KC], spy[KC];
  __shared__ int sbxy[KC], sbyx[KC], sbxx[KC], sbyy[KC], sval[KC];
  __shared__ float sla[KC], slb[KC];
  __shared__ int hbx[KC], hby[KC], basex[KC], basey[KC], curx[KC], cury[KC];
  const int tid = threadIdx.x;
  const int gtid = blockIdx.x*blockDim.x + tid;
  const int nth  = gridDim.x*blockDim.x;

  if(tid==0){
    int ox=0, oy=0, px=0, py=0; float lf=0.f;
    for(int k=0;k<KC;k++){
      int nk=p.zr[8+k], mk=p.zr[16+k];
      scx[k]=nk; scy[k]=mk;
      sox[k]=ox; soy[k]=oy; spx[k]=px; spy[k]=py;
      ox+=nk; oy+=mk; px=(px+nk+3)&~3; py=(py+mk+3)&~3;
      sla[k] = -logf(fmaxf((float)nk,1.f));
      slb[k] = -logf(fmaxf((float)mk,1.f));
      sval[k] = (nk>0 && mk>0)?1:0;
      float df = (float)nk/(float)NN - p.ftarg[k];
      lf += df*df;
    }
    sox[KC]=ox; soy[KC]=oy;
    int run=0;
    for(int k=0;k<KC;k++){ int nk=scx[k], mk=scy[k]; sbxy[k]=run; run+=nk*((mk+3)&~3); }
    for(int k=0;k<KC;k++){ int nk=scx[k], mk=scy[k]; sbyx[k]=run; run+=mk*((nk+3)&~3); }
    for(int k=0;k<KC;k++){ int nk=scx[k];            sbxx[k]=run; run+=nk*((nk+3)&~3); }
    for(int k=0;k<KC;k++){ int mk=scy[k];            sbyy[k]=run; run+=mk*((mk+3)&~3); }
    if(blockIdx.x==0){
      for(int k=0;k<KC;k++){
        p.cntx[k]=scx[k]; p.cnty[k]=scy[k];
        p.off_x[k]=sox[k]; p.off_y[k]=soy[k];
        p.pox[k]=spx[k]; p.poy[k]=spy[k];
        p.bxy[k]=sbxy[k]; p.byx[k]=sbyx[k]; p.bxx[k]=sbxx[k]; p.byy[k]=sbyy[k];
        p.la[k]=sla[k]; p.lb[k]=slb[k]; p.valid[k]=sval[k];
      }
      int trun=0;
      for(int e=0;e<32;e++){
        int seg=e>>3, k=e&7;
        int nk=scx[k], mk=scy[k];
        int nrows = (seg==0)?nk:(seg==1)?mk:(seg==2)?nk:mk;
        int rs    = (seg==0)?((mk+3)&~3):(seg==1)?((nk+3)&~3):(seg==2)?((nk+3)&~3):((mk+3)&~3);
        p.tpre[e]=trun;
        trun += ((nrows+63)>>6) * ((rs+63)>>6);
      }
      p.tpre[32]=trun;
      *p.acc = lf/(float)KC;
    }
  }
  if(tid<KC){ hbx[tid]=0; hby[tid]=0; curx[tid]=0; cury[tid]=0; }
  __syncthreads();

  // pass 1: this block's per-cluster counts (LDS atomics only)
  for(int i=gtid;i<NN;i+=nth) atomicAdd(&hbx[p.pred_x[i]],1);
  for(int j=gtid;j<MM;j+=nth) atomicAdd(&hby[p.predy[j]],1);
  __syncthreads();
  // reserve global ranges: ONE device atomic per (block,cluster)
  if(tid<KC){
    basex[tid] = sox[tid] + (hbx[tid] ? atomicAdd(&p.zr[24+tid], hbx[tid]) : 0);
    basey[tid] = soy[tid] + (hby[tid] ? atomicAdd(&p.zr[32+tid], hby[tid]) : 0);
  }
  __syncthreads();

  // pass 2: place points (LDS cursors; pack order within cluster is irrelevant)
  for(int i=gtid;i<NN;i+=nth){
    int k=p.pred_x[i];
    int pos = basex[k] + atomicAdd(&curx[k],1);
    const float4* xi=(const float4*)(p.x+i*DD);
    float4* dst=(float4*)(p.Xp+(size_t)pos*DD);
    float s=0.f;
    #pragma unroll
    for(int q=0;q<DD/4;q++){ float4 v=xi[q]; dst[q]=v;
      s += v.x*v.x+v.y*v.y+v.z*v.z+v.w*v.w; }
    p.xn[pos]=s;
  }
  for(int j=gtid;j<MM;j+=nth){
    int k=p.predy[j];
    int pos = basey[k] + atomicAdd(&cury[k],1);
    const float4* yj=(const float4*)(p.y+j*DD);
    float4* dst=(float4*)(p.Yp+(size_t)pos*DD);
    float s=0.f;
    #pragma unroll
    for(int q=0;q<DD/4;q++){ float4 v=yj[q]; dst[q]=v;
      s += v.x*v.x+v.y*v.y+v.z*v.z+v.w*v.w; }
    p.yn[pos]=s;
  }

  // per-row metadata
  for(int row=gtid; row<TOTROWS; row+=nth){
    int grp = (row>=NN) + (row>=NN+MM) + (row>=2*NN+MM);
    int pidx = row - ((grp==0)?0:(grp==1)?NN:(grp==2)?(NN+MM):(2*NN+MM));
    const int* offs = (grp==0||grp==2)? sox : soy;
    int k=0;
    #pragma unroll
    for(int q=1;q<KC;q++) if(pidx>=offs[q]) k=q;
    int r = pidx - offs[k];
    int nk=scx[k], mk=scy[k];
    int rsx=(nk+3)&~3, rsy=(mk+3)&~3;
    int coff, rs, di; float hc, fv; int hoff;
    if(grp==0){ rs=rsy; coff=sbxy[k]+r*rs; hoff=spy[k]; hc=slb[k]; di=spx[k]+r;
      fv = sval[k] ?  1.f/(float)nk : 0.f; }
    else if(grp==1){ rs=rsx; coff=sbyx[k]+r*rs; hoff=spx[k]; hc=sla[k]; di=spy[k]+r;
      fv = sval[k] ?  1.f/(float)mk : 0.f; }
    else if(grp==2){ rs=rsx; coff=sbxx[k]+r*rs; hoff=spx[k]; hc=sla[k]; di=spx[k]+r;
      fv = sval[k] ? -1.f/(float)nk : 0.f; }
    else { rs=rsy; coff=sbyy[k]+r*rs; hoff=spy[k]; hc=slb[k]; di=spy[k]+r;
      fv = sval[k] ? -1.f/(float)mk : 0.f; }
    p.meta[row] = make_int4(coff, hoff, rs, __float_as_int(hc*INVLN2F));
    p.fin[row]  = fv;
    p.dsti[row] = di;
  }
}

// ---------------- k4: LDS-tiled cost build (64x64 tiles, B transposed) ----------------
__global__ void __launch_bounds__(256) k4_cost(Params p){
  __shared__ float As[64*68];
  __shared__ float Bt[64*68];
  const int tid = threadIdx.x;
  const int T = p.tpre[32];

  for(int tile=blockIdx.x; tile<T; tile+=gridDim.x){
    int e=0;
    for(int q=1;q<32;q++) if(tile>=p.tpre[q]) e=q;
    int seg=e>>3, k=e&7;
    int nk=p.cntx[k], mk=p.cnty[k];
    int rsx=(nk+3)&~3, rsy=(mk+3)&~3;
    const float *Apts, *Bpts, *nA, *nB; int nrows, ncol, rs, base;
    if(seg==0){ Apts=p.Xp+(size_t)p.off_x[k]*DD; Bpts=p.Yp+(size_t)p.off_y[k]*DD;
      nA=p.xn+p.off_x[k]; nB=p.yn+p.off_y[k]; nrows=nk; ncol=mk; rs=rsy; base=p.bxy[k]; }
    else if(seg==1){ Apts=p.Yp+(size_t)p.off_y[k]*DD; Bpts=p.Xp+(size_t)p.off_x[k]*DD;
      nA=p.yn+p.off_y[k]; nB=p.xn+p.off_x[k]; nrows=mk; ncol=nk; rs=rsx; base=p.byx[k]; }
    else if(seg==2){ Apts=p.Xp+(size_t)p.off_x[k]*DD; Bpts=Apts;
      nA=p.xn+p.off_x[k]; nB=nA; nrows=nk; ncol=nk; rs=rsx; base=p.bxx[k]; }
    else { Apts=p.Yp+(size_t)p.off_y[k]*DD; Bpts=Apts;
      nA=p.yn+p.off_y[k]; nB=nA; nrows=mk; ncol=mk; rs=rsy; base=p.byy[k]; }
    int ntc=(rs+63)>>6;
    int lt = tile - p.tpre[e];
    int tr = lt/ntc, tc = lt - tr*ntc;

    __syncthreads();
    for(int l=tid;l<1024;l+=256){
      int row=l>>4, c4=l&15;
      int gA=tr*64+row;
      float4 va = (gA<nrows)? ((const float4*)Apts)[gA*16+c4] : make_float4(0.f,0.f,0.f,0.f);
      *(float4*)&As[row*68 + c4*4] = va;
      int gB=tc*64+row;
      float4 vb = (gB<ncol)? ((const float4*)Bpts)[gB*16+c4] : make_float4(0.f,0.f,0.f,0.f);
      Bt[(c4*4+0)*68+row]=vb.x; Bt[(c4*4+1)*68+row]=vb.y;
      Bt[(c4*4+2)*68+row]=vb.z; Bt[(c4*4+3)*68+row]=vb.w;
    }
    __syncthreads();

    int tx=tid&15, ty=tid>>4;
    float4 acc[4] = {make_float4(0,0,0,0),make_float4(0,0,0,0),
                     make_float4(0,0,0,0),make_float4(0,0,0,0)};
    for(int kk=0;kk<64;kk+=4){
      float4 a0=*(float4*)&As[(ty*4+0)*68+kk];
      float4 a1=*(float4*)&As[(ty*4+1)*68+kk];
      float4 a2=*(float4*)&As[(ty*4+2)*68+kk];
      float4 a3=*(float4*)&As[(ty*4+3)*68+kk];
      float4 b0=*(float4*)&Bt[(kk+0)*68+tx*4];
      float4 b1=*(float4*)&Bt[(kk+1)*68+tx*4];
      float4 b2=*(float4*)&Bt[(kk+2)*68+tx*4];
      float4 b3=*(float4*)&Bt[(kk+3)*68+tx*4];
      #define ACCROW(i,AI) \
        acc[i].x = fmaf(AI.x,b0.x, fmaf(AI.y,b1.x, fmaf(AI.z,b2.x, fmaf(AI.w,b3.x, acc[i].x)))); \
        acc[i].y = fmaf(AI.x,b0.y, fmaf(AI.y,b1.y, fmaf(AI.z,b2.y, fmaf(AI.w,b3.y, acc[i].y)))); \
        acc[i].z = fmaf(AI.x,b0.z, fmaf(AI.y,b1.z, fmaf(AI.z,b2.z, fmaf(AI.w,b3.z, acc[i].z)))); \
        acc[i].w = fmaf(AI.x,b0.w, fmaf(AI.y,b1.w, fmaf(AI.z,b2.w, fmaf(AI.w,b3.w, acc[i].w))));
      ACCROW(0,a0) ACCROW(1,a1) ACCROW(2,a2) ACCROW(3,a3)
      #undef ACCROW
    }

    int gc0 = tc*64 + tx*4;
    #pragma unroll
    for(int i=0;i<4;i++){
      int gr = tr*64 + ty*4 + i;
      if(gr >= nrows) continue;
      float xr = nA[gr];
      float v[4]; float d[4]={acc[i].x,acc[i].y,acc[i].z,acc[i].w};
      #pragma unroll
      for(int j=0;j<4;j++){
        int gc = gc0+j;
        v[j] = PADV;
        if(gc < ncol) v[j] = 0.5f*fmaxf(xr + nB[gc] - 2.f*d[j], 0.f);
      }
      if(gc0+3 < rs){
        *(float4*)&p.Call[(size_t)base + (size_t)gr*rs + gc0] = make_float4(v[0],v[1],v[2],v[3]);
      } else {
        for(int j=0;j<4;j++) if(gc0+j < rs) p.Call[(size_t)base + (size_t)gr*rs + gc0+j] = v[j];
      }
    }
  }
}

// value-form online-LSE step: C chunk held in registers across iterations
#define LSE_CORE(cv,pv,hi,mi,si) { \
  float w0=fmaf((pv).x-(cv).x,s1,hi), w1=fmaf((pv).y-(cv).y,s1,hi); \
  float w2=fmaf((pv).z-(cv).z,s1,hi), w3=fmaf((pv).w-(cv).w,s1,hi); \
  float lm=fmaxf(fmaxf(w0,w1),fmaxf(w2,w3)); \
  float mn=fmaxf(mi,lm); \
  si = si*exp2f(mi-mn) + (exp2f(w0-mn)+exp2f(w1-mn)) + (exp2f(w2-mn)+exp2f(w3-mn)); \
  mi = mn; }

// ---------------- k_sweep: ALL eps steps + final extrapolation + output, ONE plain kernel ----------------
// 512 blocks (2/CU co-resident), fence-free LLC barrier between Jacobi steps.
// Each wave owns 4 rows; C rows staged ONCE in registers (<=512 cols fast path),
// own-potential carried in registers; per-iteration global traffic is only the
// ~34KB of opposite-side potentials, read/written coherently at the LLC.
__global__ void __launch_bounds__(256, 3) k_sweep(Params p){
  __shared__ float sp[4];
  const int tid  = threadIdx.x;
  const int lane = tid & 63;
  const int wv   = tid >> 6;
  const int w    = blockIdx.x*4 + wv;        // wave id 0..2047
  const int rbase = w*RPW;
  const int grp = (rbase>=NN) + (rbase>=NN+MM) + (rbase>=2*NN+MM);  // groups aligned to 4

  const float* poBase; int poN; float* fam; int famN;
  if(grp==0){ poBase=p.Gab; poN=PM; fam=p.Fab; famN=PN; }
  else if(grp==1){ poBase=p.Fab; poN=PN; fam=p.Gab; famN=PM; }
  else if(grp==2){ poBase=p.Faa; poN=PN; fam=p.Faa; famN=PN; }
  else          { poBase=p.Gbb; poN=PM; fam=p.Gbb; famN=PM; }

  int coff[RPW], hof[RPW], rs[RPW], dst[RPW];
  float h[RPW], fv[RPW];
  int rsm = 0;
  #pragma unroll
  for(int j=0;j<RPW;j++){
    int4 mt = p.meta[rbase+j];
    coff[j]=mt.x; hof[j]=mt.y; rs[j]=mt.z; h[j]=__int_as_float(mt.w);
    dst[j]=p.dsti[rbase+j]; fv[j]=p.fin[rbase+j];
    rsm = rs[j]>rsm ? rs[j] : rsm;
  }

  // ---- stage C rows in registers (fast path: rsm <= 512 -> 2 chunks/lane/row) ----
  const int c0a = lane*4, c0b = lane*4 + 256;
  const bool staged = (rsm <= 512);   // wave-uniform
  const bool two    = (rsm > 256);    // wave-uniform
  const float4 PAD4 = make_float4(PADV,PADV,PADV,PADV);
  float4 cva[RPW], cvb[RPW];
  #pragma unroll
  for(int j=0;j<RPW;j++){ cva[j]=PAD4; cvb[j]=PAD4; }
  if(staged){
    #pragma unroll
    for(int j=0;j<RPW;j++){
      if(c0a<rs[j]) cva[j] = *(const float4*)(p.Call+coff[j]+c0a);
      if(two && c0b<rs[j]) cvb[j] = *(const float4*)(p.Call+coff[j]+c0b);
    }
  }
  // Padded lanes (cv=PADV, pv=0): w is hugely negative/-inf; their si terms are
  // annihilated by exp2f(m-M) in the cross-lane rescale -> exact match with the
  // guarded stream loop.

  const double EMIND = 0.05*0.05, S2D = 0.8*0.8;
  float f[RPW];
  #pragma unroll
  for(int j=0;j<RPW;j++) f[j]=0.f;

  double e = 16.0; int it = 0;
  for(;;){
    const bool last = !(e > EMIND);
    const float eps = last ? (float)EMIND : (float)e;
    const float s1 = (1.0f/eps)*INVLN2F;
    const int cur = it & 1;
    const float* po = poBase + cur*poN;

    float m[RPW], s[RPW];
    #pragma unroll
    for(int j=0;j<RPW;j++){ m[j]=-3.4e38f; s[j]=0.f; }
    if(staged){
      #pragma unroll
      for(int j=0;j<RPW;j++){
        float4 pv = (c0a<rs[j])? ld_coh4(po+hof[j]+c0a) : make_float4(0.f,0.f,0.f,0.f);
        LSE_CORE(cva[j], pv, h[j], m[j], s[j])
      }
      if(two){
        #pragma unroll
        for(int j=0;j<RPW;j++){
          float4 pv = (c0b<rs[j])? ld_coh4(po+hof[j]+c0b) : make_float4(0.f,0.f,0.f,0.f);
          LSE_CORE(cvb[j], pv, h[j], m[j], s[j])
        }
      }
    } else {
      for(int c0=lane*4; c0<rsm; c0+=256){
        #pragma unroll
        for(int j=0;j<RPW;j++){
          if(c0<rs[j]){
            float4 cv=*(const float4*)(p.Call+coff[j]+c0);
            float4 pv=ld_coh4(po+hof[j]+c0);
            LSE_CORE(cv, pv, h[j], m[j], s[j])
          }
        }
      }
    }
    #pragma unroll
    for(int j=0;j<RPW;j++){
      float M=wredmax(m[j]);
      float S=wredsum(s[j]*exp2f(m[j]-M));
      f[j] = 0.5f*(f[j] + (-eps*LN2F*(M + log2f(S))));
    }
    if(lane==0){
      float* fn = fam + (1-cur)*famN;
      #pragma unroll
      for(int j=0;j<RPW;j++) st_coh(&fn[dst[j]], f[j]);
    }
    ++it;
    gbar(p.bsync, it);
    if(last) break;
    e *= S2D;
  }

  // ---- final extrapolation at eps_min (cur = ne&1 = it&1), per-block partial ----
  {
    const float eps = (float)EMIND;
    const float s1 = (1.0f/eps)*INVLN2F;
    const int cur = it & 1;
    const float* po = poBase + cur*poN;

    float m[RPW], s[RPW];
    #pragma unroll
    for(int j=0;j<RPW;j++){ m[j]=-3.4e38f; s[j]=0.f; }
    if(staged){
      #pragma unroll
      for(int j=0;j<RPW;j++){
        float4 pv = (c0a<rs[j])? ld_coh4(po+hof[j]+c0a) : make_float4(0.f,0.f,0.f,0.f);
        LSE_CORE(cva[j], pv, h[j], m[j], s[j])
      }
      if(two){
        #pragma unroll
        for(int j=0;j<RPW;j++){
          float4 pv = (c0b<rs[j])? ld_coh4(po+hof[j]+c0b) : make_float4(0.f,0.f,0.f,0.f);
          LSE_CORE(cvb[j], pv, h[j], m[j], s[j])
        }
      }
    } else {
      for(int c0=lane*4; c0<rsm; c0+=256){
        #pragma unroll
        for(int j=0;j<RPW;j++){
          if(c0<rs[j]){
            float4 cv=*(const float4*)(p.Call+coff[j]+c0);
            float4 pv=ld_coh4(po+hof[j]+c0);
            LSE_CORE(cv, pv, h[j], m[j], s[j])
          }
        }
      }
    }
    float pr = 0.f;
    #pragma unroll
    for(int j=0;j<RPW;j++){
      float M=wredmax(m[j]);
      float S=wredsum(s[j]*exp2f(m[j]-M));
      if(fv[j]!=0.f) pr += fv[j]*(-eps*LN2F*(M + log2f(S)));
    }
    if(lane==0) sp[wv] = pr;
    __syncthreads();
    if(tid==0)
      st_coh(&p.part[blockIdx.x], sp[0]+sp[1]+sp[2]+sp[3]);
  }
  gbar(p.bsync, it+1);

  // ---- output: block 0 sums partials + filling loss ----
  if(blockIdx.x==0){
    float s=0.f;
    for(int i=tid;i<NSW;i+=256) s += ld_coh(&p.part[i]);
    s = wredsum(s);
    if((tid&63)==0) sp[tid>>6]=s;
    __syncthreads();
    if(tid==0)
      p.out[0] = sp[0]+sp[1]+sp[2]+sp[3] + *p.acc;
  }
}

extern "C" void kernel_launch(void* const* d_in, const int* in_sizes, int n_in,
                              void* d_out, int out_size, void* d_ws, size_t ws_size,
                              hipStream_t stream)
{
  Params p;
  p.x       = (const float*)d_in[0];
  p.centers = (const float*)d_in[1];
  p.ftarg   = (const float*)d_in[2];
  p.y       = (const float*)d_in[3];
  p.predy   = (const int*)d_in[4];
  p.out     = (float*)d_out;

  char* w = (char*)d_ws; size_t o = 0;
  auto A = [&](size_t bytes)->char*{ char* r = w + o; o = (o + bytes + 255) & ~(size_t)255; return r; };
  p.zr   =(int*)A(64*4);
  p.pred_x=(int*)A(NN*4);
  p.cntx =(int*)A(KC*4); p.cnty=(int*)A(KC*4);
  p.off_x=(int*)A(KC*4); p.off_y=(int*)A(KC*4);
  p.pox  =(int*)A(KC*4); p.poy =(int*)A(KC*4);
  p.bxy  =(int*)A(KC*4); p.byx =(int*)A(KC*4);
  p.bxx  =(int*)A(KC*4); p.byy =(int*)A(KC*4);
  p.tpre =(int*)A(33*4);
  p.la=(float*)A(KC*4); p.lb=(float*)A(KC*4); p.valid=(int*)A(KC*4);
  p.acc=(float*)A(4);
  p.part=(float*)A(NSW*4);
  p.Xp=(float*)A((size_t)NN*DD*4); p.Yp=(float*)A((size_t)MM*DD*4);
  p.xn=(float*)A(NN*4); p.yn=(float*)A(MM*4);
  p.Fab=(float*)A((size_t)2*PN*4); p.Faa=(float*)A((size_t)2*PN*4);
  p.Gab=(float*)A((size_t)2*PM*4); p.Gbb=(float*)A((size_t)2*PM*4);
  p.meta=(int4*)A((size_t)TOTROWS*16);
  p.fin =(float*)A((size_t)TOTROWS*4);
  p.dsti=(int*)A((size_t)TOTROWS*4);
  p.bsync=(int*)A((64+NSW)*4);
  p.Call=(float*)A((size_t)CPAD*4);

  hipMemsetAsync(p.zr, 0, 64*4, stream);
  hipLaunchKernelGGL(k_pred,  dim3(16),  dim3(256), 0, stream, p);
  hipLaunchKernelGGL(k_pack,  dim3(32),  dim3(256), 0, stream, p);
  hipLaunchKernelGGL(k4_cost, dim3(512), dim3(256), 0, stream, p);
  hipLaunchKernelGGL(k_sweep, dim3(NSW), dim3(256), 0, stream, p);
}